// Round 1
// baseline (361.107 us; speedup 1.0000x reference)
//
#include <hip/hip_runtime.h>
#include <hip/hip_bf16.h>

typedef float  f32x16 __attribute__((ext_vector_type(16)));
typedef float  f32x4  __attribute__((ext_vector_type(4)));
typedef short  s16x8  __attribute__((ext_vector_type(8)));
typedef unsigned int u32x4 __attribute__((ext_vector_type(4)));

#define B_   4
#define SQ_  2048
#define SK_  2048
#define H_   16
#define D_   128
#define RS   (H_*D_)                 // 2048 floats per seq step
#define QSCALE 0.12751219658526f     // (1/sqrt(128)) * log2(e)  -> scores in log2 domain
#define KVB  64
#define QTILE 256
#define KB_BYTES  (64*128*2)         // 16 KiB bf16 K tile
#define BUF_BYTES (2*KB_BYTES)       // K tile + V^T tile

__device__ __forceinline__ unsigned pk_bf16(float lo, float hi) {
    unsigned r;
    asm("v_cvt_pk_bf16_f32 %0, %1, %2" : "=v"(r) : "v"(lo), "v"(hi));
    return r;
}
__device__ __forceinline__ void swap32u(unsigned &a, unsigned &b) {
    // a' = [a.lo32 | b.lo32] , b' = [a.hi32 | b.hi32]
    asm("v_permlane32_swap_b32 %0, %1" : "+v"(a), "+v"(b));
}
// K tile: [64 rows][128 d] bf16, row stride 256 B, XOR swizzle on 16B slots
__device__ __forceinline__ int kaddr(int row, int colb) {
    return row * 256 + (colb ^ ((row & 7) << 4));
}
// V^T tile: [128 d][64 kv] bf16, row stride 128 B; swizzle spreads both the
// b128 column reads (rows d = lane) and the b32 transposing writes
__device__ __forceinline__ int vaddr(int d, int colb) {
    return d * 128 + (colb ^ ((((d & 7) ^ ((d >> 3) & 7))) << 4));
}

__global__ __launch_bounds__(512, 2)
void fattn_fwd(const float* __restrict__ Qg, const float* __restrict__ Kg,
               const float* __restrict__ Vg, float* __restrict__ Og)
{
    __shared__ __align__(16) char smem[2 * BUF_BYTES];   // 64 KiB double buffer

    const int tid = threadIdx.x;
    const int w   = tid >> 6;
    const int l   = tid & 63;
    const int l31 = l & 31;
    const int hi  = l >> 5;

    // ---- block decode: XCD swizzle (8 q-tiles of one (b,h) per XCD) +
    //      causal load balance (tiles paired so each CU's two blocks sum to 7)
    const int i    = blockIdx.x;
    const int orig = (i & 7) * 64 + (i >> 3);          // bijective, 512 blocks
    const int bh   = orig >> 3;
    const int j    = orig & 7;
    const int tile = ((bh >> 2) & 1) ? j : 7 - j;
    const int b    = bh >> 4;
    const int h    = bh & 15;

    const int q0 = tile * QTILE;
    const int nt = (q0 + QTILE) / KVB;                 // KV tiles to process

    const size_t base = ((size_t)b * SK_ * H_ + h) * D_;
    const float* Kp = Kg + base;
    const float* Vp = Vg + base;
    const float* Qp = Qg + base;
    float*       Op = Og + base;

    // ---- Q fragments (B operand: col=q=l%32, k = 16*sl + 8*hi + e) ----
    const int qrow = q0 + w * 32 + l31;
    const float* qptr = Qp + (size_t)qrow * RS + hi * 8;
    s16x8 qf[8];
#pragma unroll
    for (int sl = 0; sl < 8; ++sl) {
        f32x4 a = *(const f32x4*)(qptr + sl * 16);
        f32x4 c = *(const f32x4*)(qptr + sl * 16 + 4);
        u32x4 u;
        u[0] = pk_bf16(a[0] * QSCALE, a[1] * QSCALE);
        u[1] = pk_bf16(a[2] * QSCALE, a[3] * QSCALE);
        u[2] = pk_bf16(c[0] * QSCALE, c[1] * QSCALE);
        u[3] = pk_bf16(c[2] * QSCALE, c[3] * QSCALE);
        qf[sl] = __builtin_bit_cast(s16x8, u);
    }

    // ---- staging coordinates ----
    const int krow = tid >> 3;            // K: 1 row x 16 d per thread
    const int kc   = (tid & 7) * 16;
    const int vkv  = (tid >> 4) * 2;      // V: 2 rows x 8 d per thread (pairs for b32 VT writes)
    const int vc   = (tid & 15) * 8;
    const float* kgp = Kp + (size_t)krow * RS + kc;
    const float* vgp = Vp + (size_t)vkv * RS + vc;

    // ---- accumulators: O^T, lane holds q=l&31 fixed, d = 32*db + crow(r,hi) ----
    f32x16 oacc[4];
#pragma unroll
    for (int d = 0; d < 4; ++d)
#pragma unroll
        for (int r = 0; r < 16; ++r) oacc[d][r] = 0.f;
    float m_run = -1e30f, l_run = 0.f;

    // ---- prologue: stage tile 0 into buffer 0 ----
    {
        f32x4 kr0 = *(const f32x4*)(kgp + 0);
        f32x4 kr1 = *(const f32x4*)(kgp + 4);
        f32x4 kr2 = *(const f32x4*)(kgp + 8);
        f32x4 kr3 = *(const f32x4*)(kgp + 12);
        f32x4 va0 = *(const f32x4*)(vgp + 0);
        f32x4 va1 = *(const f32x4*)(vgp + 4);
        f32x4 vb0 = *(const f32x4*)(vgp + RS);
        f32x4 vb1 = *(const f32x4*)(vgp + RS + 4);
        char* kb = smem;
        char* vb = smem + KB_BYTES;
        u32x4 u0, u1;
        u0[0] = pk_bf16(kr0[0], kr0[1]); u0[1] = pk_bf16(kr0[2], kr0[3]);
        u0[2] = pk_bf16(kr1[0], kr1[1]); u0[3] = pk_bf16(kr1[2], kr1[3]);
        u1[0] = pk_bf16(kr2[0], kr2[1]); u1[1] = pk_bf16(kr2[2], kr2[3]);
        u1[2] = pk_bf16(kr3[0], kr3[1]); u1[3] = pk_bf16(kr3[2], kr3[3]);
        *(u32x4*)(kb + kaddr(krow, kc * 2))      = u0;
        *(u32x4*)(kb + kaddr(krow, kc * 2 + 16)) = u1;
#pragma unroll
        for (int e = 0; e < 4; ++e) {
            *(unsigned*)(vb + vaddr(vc + e,     vkv * 2)) = pk_bf16(va0[e], vb0[e]);
            *(unsigned*)(vb + vaddr(vc + 4 + e, vkv * 2)) = pk_bf16(va1[e], vb1[e]);
        }
    }
    __syncthreads();

    const int qmaxw = q0 + w * 32 + 31;

    for (int t = 0; t < nt; ++t) {
        const int  nxt = t + 1;
        const bool have_next = nxt < nt;

        // T14: issue next tile's global loads BEFORE compute
        f32x4 kr0, kr1, kr2, kr3, va0, va1, vb0, vb1;
        if (have_next) {
            const float* kp2 = kgp + (size_t)nxt * KVB * RS;
            const float* vp2 = vgp + (size_t)nxt * KVB * RS;
            kr0 = *(const f32x4*)(kp2 + 0);
            kr1 = *(const f32x4*)(kp2 + 4);
            kr2 = *(const f32x4*)(kp2 + 8);
            kr3 = *(const f32x4*)(kp2 + 12);
            va0 = *(const f32x4*)(vp2 + 0);
            va1 = *(const f32x4*)(vp2 + 4);
            vb0 = *(const f32x4*)(vp2 + RS);
            vb1 = *(const f32x4*)(vp2 + RS + 4);
        }

        const int kvg = t * KVB;
        if (kvg <= qmaxw) {                       // wave-uniform causal skip
            const char* kb = smem + (t & 1) * BUF_BYTES;
            const char* vb = kb + KB_BYTES;

            // ---- QK^T (swapped): S^T[kv][q] ----
            f32x16 s0, s1;
#pragma unroll
            for (int r = 0; r < 16; ++r) { s0[r] = 0.f; s1[r] = 0.f; }
            __builtin_amdgcn_s_setprio(1);
#pragma unroll
            for (int sl = 0; sl < 8; ++sl) {
                const int colb = 32 * sl + 16 * hi;
                s16x8 ka0 = *(const s16x8*)(kb + kaddr(l31,      colb));
                s16x8 ka1 = *(const s16x8*)(kb + kaddr(32 + l31, colb));
                s0 = __builtin_amdgcn_mfma_f32_32x32x16_bf16(ka0, qf[sl], s0, 0, 0, 0);
                s1 = __builtin_amdgcn_mfma_f32_32x32x16_bf16(ka1, qf[sl], s1, 0, 0, 0);
            }
            __builtin_amdgcn_s_setprio(0);

            // ---- causal mask + row max (q = l&31 is lane-local) ----
            float pm0 = -1e30f, pm1 = -1e30f, pm2 = -1e30f, pm3 = -1e30f;
#pragma unroll
            for (int r = 0; r < 16; ++r) {
                const int crow = (r & 3) + 8 * (r >> 2) + 4 * hi;
                const int kva  = kvg + crow;
                if (kva      > qrow) s0[r] = -1e30f;
                if (kva + 32 > qrow) s1[r] = -1e30f;
                const float mr = fmaxf(s0[r], s1[r]);
                if ((r & 3) == 0) pm0 = fmaxf(pm0, mr);
                if ((r & 3) == 1) pm1 = fmaxf(pm1, mr);
                if ((r & 3) == 2) pm2 = fmaxf(pm2, mr);
                if ((r & 3) == 3) pm3 = fmaxf(pm3, mr);
            }
            float pmax = fmaxf(fmaxf(pm0, pm1), fmaxf(pm2, pm3));
            pmax = fmaxf(pmax, __shfl_xor(pmax, 32));

            // ---- defer-max (T13, THR=8 in log2 domain) ----
            if (__any(pmax > m_run + 8.0f)) {
                const float mnew = fmaxf(m_run, pmax);
                const float f = exp2f(m_run - mnew);
                m_run = mnew;
                l_run *= f;
#pragma unroll
                for (int d = 0; d < 4; ++d)
#pragma unroll
                    for (int r = 0; r < 16; ++r) oacc[d][r] *= f;
            }

            // ---- exp2 + row sum ----
            float ps0 = 0.f, ps1 = 0.f, ps2 = 0.f, ps3 = 0.f;
#pragma unroll
            for (int r = 0; r < 16; ++r) {
                s0[r] = exp2f(s0[r] - m_run);
                s1[r] = exp2f(s1[r] - m_run);
                const float sr = s0[r] + s1[r];
                if ((r & 3) == 0) ps0 += sr;
                if ((r & 3) == 1) ps1 += sr;
                if ((r & 3) == 2) ps2 += sr;
                if ((r & 3) == 3) ps3 += sr;
            }
            float psum = (ps0 + ps1) + (ps2 + ps3);
            psum += __shfl_xor(psum, 32);
            l_run += psum;

            // ---- T12: P -> bf16 PV B-operand via cvt_pk + permlane32_swap ----
            s16x8 pb[4];
            {
                unsigned w00 = pk_bf16(s0[0],  s0[1]);
                unsigned w01 = pk_bf16(s0[2],  s0[3]);
                unsigned w10 = pk_bf16(s0[4],  s0[5]);
                unsigned w11 = pk_bf16(s0[6],  s0[7]);
                unsigned w20 = pk_bf16(s0[8],  s0[9]);
                unsigned w21 = pk_bf16(s0[10], s0[11]);
                unsigned w30 = pk_bf16(s0[12], s0[13]);
                unsigned w31 = pk_bf16(s0[14], s0[15]);
                swap32u(w00, w10); swap32u(w01, w11);
                swap32u(w20, w30); swap32u(w21, w31);
                u32x4 p0; p0[0] = w00; p0[1] = w01; p0[2] = w10; p0[3] = w11;
                u32x4 p1; p1[0] = w20; p1[1] = w21; p1[2] = w30; p1[3] = w31;
                pb[0] = __builtin_bit_cast(s16x8, p0);
                pb[1] = __builtin_bit_cast(s16x8, p1);
                unsigned x00 = pk_bf16(s1[0],  s1[1]);
                unsigned x01 = pk_bf16(s1[2],  s1[3]);
                unsigned x10 = pk_bf16(s1[4],  s1[5]);
                unsigned x11 = pk_bf16(s1[6],  s1[7]);
                unsigned x20 = pk_bf16(s1[8],  s1[9]);
                unsigned x21 = pk_bf16(s1[10], s1[11]);
                unsigned x30 = pk_bf16(s1[12], s1[13]);
                unsigned x31 = pk_bf16(s1[14], s1[15]);
                swap32u(x00, x10); swap32u(x01, x11);
                swap32u(x20, x30); swap32u(x21, x31);
                u32x4 p2; p2[0] = x00; p2[1] = x01; p2[2] = x10; p2[3] = x11;
                u32x4 p3; p3[0] = x20; p3[1] = x21; p3[2] = x30; p3[3] = x31;
                pb[2] = __builtin_bit_cast(s16x8, p2);
                pb[3] = __builtin_bit_cast(s16x8, p3);
            }

            // ---- PV: O^T[d][q] += V^T[d][kv] * P^T[kv][q] ----
            __builtin_amdgcn_s_setprio(1);
#pragma unroll
            for (int db = 0; db < 4; ++db) {
                const int d = 32 * db + l31;
#pragma unroll
                for (int ks = 0; ks < 4; ++ks) {
                    s16x8 va = *(const s16x8*)(vb + vaddr(d, 32 * ks + 16 * hi));
                    oacc[db] = __builtin_amdgcn_mfma_f32_32x32x16_bf16(va, pb[ks], oacc[db], 0, 0, 0);
                }
            }
            __builtin_amdgcn_s_setprio(0);
        }

        __syncthreads();
        if (have_next) {   // write next tile into the other buffer
            char* kb = smem + (nxt & 1) * BUF_BYTES;
            char* vb = kb + KB_BYTES;
            u32x4 u0, u1;
            u0[0] = pk_bf16(kr0[0], kr0[1]); u0[1] = pk_bf16(kr0[2], kr0[3]);
            u0[2] = pk_bf16(kr1[0], kr1[1]); u0[3] = pk_bf16(kr1[2], kr1[3]);
            u1[0] = pk_bf16(kr2[0], kr2[1]); u1[1] = pk_bf16(kr2[2], kr2[3]);
            u1[2] = pk_bf16(kr3[0], kr3[1]); u1[3] = pk_bf16(kr3[2], kr3[3]);
            *(u32x4*)(kb + kaddr(krow, kc * 2))      = u0;
            *(u32x4*)(kb + kaddr(krow, kc * 2 + 16)) = u1;
#pragma unroll
            for (int e = 0; e < 4; ++e) {
                *(unsigned*)(vb + vaddr(vc + e,     vkv * 2)) = pk_bf16(va0[e], vb0[e]);
                *(unsigned*)(vb + vaddr(vc + 4 + e, vkv * 2)) = pk_bf16(va1[e], vb1[e]);
            }
        }
        __syncthreads();
    }

    // ---- epilogue: O = O^T_acc / l, written as float4 runs along d ----
    const float inv = 1.0f / l_run;
    float* op = Op + (size_t)qrow * RS;
#pragma unroll
    for (int db = 0; db < 4; ++db)
#pragma unroll
        for (int rq = 0; rq < 4; ++rq) {
            f32x4 o4;
            o4[0] = oacc[db][4 * rq + 0] * inv;
            o4[1] = oacc[db][4 * rq + 1] * inv;
            o4[2] = oacc[db][4 * rq + 2] * inv;
            o4[3] = oacc[db][4 * rq + 3] * inv;
            *(f32x4*)(op + 32 * db + 8 * rq + 4 * hi) = o4;
        }
}

extern "C" void kernel_launch(void* const* d_in, const int* in_sizes, int n_in,
                              void* d_out, int out_size, void* d_ws, size_t ws_size,
                              hipStream_t stream) {
    const float* Q = (const float*)d_in[0];
    const float* K = (const float*)d_in[1];
    const float* V = (const float*)d_in[2];
    float* O = (float*)d_out;
    (void)in_sizes; (void)n_in; (void)out_size; (void)d_ws; (void)ws_size;
    dim3 grid(B_ * H_ * (SQ_ / QTILE));   // 512 blocks
    dim3 block(512);
    hipLaunchKernelGGL(fattn_fwd, grid, block, 0, stream, Q, K, V, O);
}